// Round 7
// baseline (5258.590 us; speedup 1.0000x reference)
//
#include <hip/hip_runtime.h>
#include <hip/hip_cooperative_groups.h>
#include <math.h>

namespace cg = cooperative_groups;

#define B_    16
#define H_    16
#define N_    4096
#define T_    8
#define DS_   256
#define DID_  128
#define L_    8
#define K_    32
#define DHID_ 1024
#define DSTEER_ 896
#define QH_   512
#define QO_   256
#define NW_   256   // B*H walkers
#define SLOTS_ 512  // chunk-slot space: 16 chunks x 32 slots
#define SCORE_SCALE 0.022097086912079608f  // 1/(8*sqrt(32))

struct KArgs {
    const float *s_in, *node_id, *ws_in, *token, *norm_w;
    const float *W1, *b1, *W2, *b2;
    const float *qw1, *qb1, *qw2, *qb2, *kw1, *kb1, *kw2, *kb2;
    const int *walker_pos, *plane_idx, *neighbors;
    float *out_motor, *out_s, *out_pos, *out_ws, *out_co, *out_vc, *out_lb;
    float *keys, *kh, *steer, *steerT, *h1p, *q1p, *c2p, *q2p, *mp_all;
    int *pos;
};

__device__ __forceinline__ float gelu_exact(float x) {
    return 0.5f * x * (1.0f + erff(x * 0.70710678118654752f));
}

#define FMA4(c, b, a) { c.x = fmaf(b.x, (a), c.x); c.y = fmaf(b.y, (a), c.y); \
                        c.z = fmaf(b.z, (a), c.z); c.w = fmaf(b.w, (a), c.w); }

__device__ __forceinline__ void gelu4(float4& v) {
    v.x = gelu_exact(v.x); v.y = gelu_exact(v.y);
    v.z = gelu_exact(v.z); v.w = gelu_exact(v.w);
}

__device__ __forceinline__ void rgemm_inner(
    const float* __restrict__ a0, const float* __restrict__ a1,
    const float* __restrict__ bp, int ldb, int K,
    float4& c0, float4& c1)
{
    for (int k = 0; k < K; k += 8) {
        const float4 a0l = *reinterpret_cast<const float4*>(a0 + k);
        const float4 a0h = *reinterpret_cast<const float4*>(a0 + k + 4);
        const float4 a1l = *reinterpret_cast<const float4*>(a1 + k);
        const float4 a1h = *reinterpret_cast<const float4*>(a1 + k + 4);
        const float* b8 = bp + (size_t)k * ldb;
#define KSTEP(o, av0, av1) { float4 bv = *reinterpret_cast<const float4*>(b8 + (size_t)(o) * ldb); \
                             FMA4(c0, bv, av0); FMA4(c1, bv, av1); }
        KSTEP(0, a0l.x, a1l.x)
        KSTEP(1, a0l.y, a1l.y)
        KSTEP(2, a0l.z, a1l.z)
        KSTEP(3, a0l.w, a1l.w)
        KSTEP(4, a0h.x, a1h.x)
        KSTEP(5, a0h.y, a1h.y)
        KSTEP(6, a0h.z, a1h.z)
        KSTEP(7, a0h.w, a1h.w)
#undef KSTEP
    }
}

// ---------------- per-block LDS bucketing (idempotent, inputs-only) ---------

struct Buckets {
    int porder[8 * NW_];
    int cnt[8];
    int cbase[16];
    int chunk_plane[16];
    int slot_of[NW_];
    int nchunks;
};

__device__ void build_buckets(const int* __restrict__ plane_idx, int tid, Buckets* bk)
{
    int wave = tid >> 6, lane = tid & 63;
    for (int pp = wave; pp < 8; pp += 4) {
        int base = 0;
        for (int c0 = 0; c0 < NW_; c0 += 64) {
            int w = c0 + lane;
            bool hit = (plane_idx[w] == pp);
            unsigned long long mask = __ballot(hit);
            if (hit) {
                int rank = __popcll(mask & ((1ull << lane) - 1ull));
                bk->porder[pp * NW_ + base + rank] = w;
            }
            base += __popcll(mask);
        }
        if (lane == 0) bk->cnt[pp] = base;
    }
    __syncthreads();
    if (tid == 0) {
        int nc = 0;
        for (int p = 0; p < 8; ++p)
            for (int s0 = 0; s0 < bk->cnt[p]; s0 += 32) {
                bk->chunk_plane[nc] = p; bk->cbase[nc] = s0; ++nc;
            }
        bk->nchunks = nc;
        for (int c = nc; c < 16; ++c) { bk->chunk_plane[c] = 0; bk->cbase[c] = 0; }
    }
    __syncthreads();
    int nc = bk->nchunks;
    for (int idx = tid; idx < 512; idx += 256) {
        int c = idx >> 5, i = idx & 31;
        if (c < nc) {
            int p = bk->chunk_plane[c];
            int r = bk->cbase[c] + i;
            if (r < bk->cnt[p]) bk->slot_of[bk->porder[p * NW_ + r]] = c * 32 + i;
        }
    }
    __syncthreads();
}

// ---------------- phase bodies ----------------

__device__ void dev_biginit(const KArgs& a, int gid, int stride) {
    const float4 z = {0.f, 0.f, 0.f, 0.f};
    float4* co4 = reinterpret_cast<float4*>(a.out_co);
    float4* s4o = reinterpret_cast<float4*>(a.out_s);
    const float4* s4i = reinterpret_cast<const float4*>(a.s_in);
    for (int i = gid; i < 4194304; i += stride) co4[i] = z;
    for (int i = gid; i < 4194304; i += stride) s4o[i] = s4i[i];
    float4* m4 = reinterpret_cast<float4*>(a.out_motor);
    for (int i = gid; i < 8192; i += stride) m4[i] = z;
    float4* w4o = reinterpret_cast<float4*>(a.out_ws);
    const float4* w4i = reinterpret_cast<const float4*>(a.ws_in);
    for (int i = gid; i < 16384; i += stride) w4o[i] = w4i[i];
    float4* v4 = reinterpret_cast<float4*>(a.out_vc);
    for (int i = gid; i < 1024; i += stride) v4[i] = z;
    if (gid == 0) a.out_lb[0] = 0.f;
}

__device__ void dev_keysA(const KArgs& a, int u, int tid) {
    int rt = u >> 3, ct = u & 7;
    int tr = tid >> 4, tc = tid & 15;
    int row = rt * 32 + tr * 2, col = ct * 64 + tc * 4;
    const float* a0 = a.node_id + (size_t)row * DID_;
    float4 c0 = {0.f,0.f,0.f,0.f}, c1 = {0.f,0.f,0.f,0.f};
    rgemm_inner(a0, a0 + DID_, a.kw1 + col, QH_, DID_, c0, c1);
    float4 bv = *reinterpret_cast<const float4*>(a.kb1 + col);
    c0.x += bv.x; c0.y += bv.y; c0.z += bv.z; c0.w += bv.w;
    c1.x += bv.x; c1.y += bv.y; c1.z += bv.z; c1.w += bv.w;
    gelu4(c0); gelu4(c1);
    *reinterpret_cast<float4*>(a.kh + (size_t)row * QH_ + col) = c0;
    *reinterpret_cast<float4*>(a.kh + (size_t)(row + 1) * QH_ + col) = c1;
}

__device__ void dev_keysB(const KArgs& a, int u, int tid) {
    int rt = u >> 2, ct = u & 3;
    int tr = tid >> 4, tc = tid & 15;
    int row = rt * 32 + tr * 2, col = ct * 64 + tc * 4;
    const float* a0 = a.kh + (size_t)row * QH_;
    float4 c0 = {0.f,0.f,0.f,0.f}, c1 = {0.f,0.f,0.f,0.f};
    rgemm_inner(a0, a0 + QH_, a.kw2 + col, QO_, QH_, c0, c1);
    float4 bv = *reinterpret_cast<const float4*>(a.kb2 + col);
    c0.x += bv.x; c0.y += bv.y; c0.z += bv.z; c0.w += bv.w;
    c1.x += bv.x; c1.y += bv.y; c1.z += bv.z; c1.w += bv.w;
    *reinterpret_cast<float4*>(a.keys + (size_t)row * QO_ + col) = c0;
    *reinterpret_cast<float4*>(a.keys + (size_t)(row + 1) * QO_ + col) = c1;
}

__device__ void dev_steer(const KArgs& a, int w, int tid, int t, const Buckets* bk) {
    int b = w >> 4;
    int p = a.pos[w];                 // block-local: walker w always on block w
    int slot = bk->slot_of[w];
    float sc = a.out_s[((size_t)b * N_ + p) * DS_ + tid];
    float v = sc * sc;
    for (int off = 32; off > 0; off >>= 1) v += __shfl_down(v, off);
    __shared__ float red[4];
    if ((tid & 63) == 0) red[tid >> 6] = v;
    __syncthreads();
    float tot = red[0] + red[1] + red[2] + red[3];
    float r = rsqrtf(tot * (1.0f / DS_) + 1e-6f);
    float* st = a.steer + (size_t)w * DSTEER_;
    float v0 = sc * r * a.norm_w[tid];
    float v2 = a.out_ws[(size_t)w * DS_ + tid];
    float v3 = a.token[((size_t)b * T_ + t) * DS_ + tid];
    st[tid] = v0;
    st[384 + tid] = v2;
    st[640 + tid] = v3;
    a.steerT[(size_t)tid * SLOTS_ + slot] = v0;
    a.steerT[(size_t)(384 + tid) * SLOTS_ + slot] = v2;
    a.steerT[(size_t)(640 + tid) * SLOTS_ + slot] = v3;
    if (tid < 128) {
        float v1 = a.node_id[(size_t)p * DID_ + tid];
        st[256 + tid] = v1;
        a.steerT[(size_t)(256 + tid) * SLOTS_ + slot] = v1;
    }
    __syncthreads();
}

// K-split x8. units 0..511: q hidden (K=112); 512..2559: content hidden (K=112).
__device__ void dev_l1(const KArgs& a, int u, int tid, const Buckets* bk) {
    float4 c0 = {0.f,0.f,0.f,0.f}, c1 = {0.f,0.f,0.f,0.f};
    if (u < 512) {
        int kp = u & 7, tile = u >> 3;
        int rt = tile >> 3, ct = tile & 7;
        int tr = tid >> 4, tc = tid & 15;
        int row = rt * 32 + tr * 2, col = ct * 64 + tc * 4;
        const float* a0 = a.steer + (size_t)row * DSTEER_ + kp * 112;
        rgemm_inner(a0, a0 + DSTEER_, a.qw1 + (size_t)(kp * 112) * QH_ + col, QH_, 112, c0, c1);
        float* o = a.q1p + (size_t)kp * 131072;
        *reinterpret_cast<float4*>(o + (size_t)row * QH_ + col) = c0;
        *reinterpret_cast<float4*>(o + (size_t)(row + 1) * QH_ + col) = c1;
    } else {
        int b2 = u - 512;
        int kp = b2 & 7, tile = b2 >> 3;
        int c = tile >> 4, jt = tile & 15;
        if (c >= bk->nchunks) return;
        int p = bk->chunk_plane[c];
        int tr = tid >> 3, tc = tid & 7;
        int J = jt * 64 + tr * 2;
        int slot = c * 32 + tc * 4;
        const float* a0 = a.W1 + ((size_t)p * DHID_ + J) * DSTEER_ + kp * 112;
        rgemm_inner(a0, a0 + DSTEER_, a.steerT + (size_t)(kp * 112) * SLOTS_ + slot, SLOTS_, 112, c0, c1);
        float* o = a.h1p + (size_t)kp * 524288;
        *reinterpret_cast<float4*>(o + (size_t)J * SLOTS_ + slot) = c0;
        *reinterpret_cast<float4*>(o + (size_t)(J + 1) * SLOTS_ + slot) = c1;
    }
}

__device__ void dev_comb1(const KArgs& a, int idx, const Buckets* bk) {
    if (idx < 131072) {                            // content: [1024 J][512 slots]
        int J = idx >> 7, s4 = (idx & 127) << 2;
        size_t off = (size_t)J * SLOTS_ + s4;
        float4 acc = {0.f,0.f,0.f,0.f};
#pragma unroll
        for (int kp = 0; kp < 8; ++kp) {
            float4 v = *reinterpret_cast<const float4*>(a.h1p + (size_t)kp * 524288 + off);
            acc.x += v.x; acc.y += v.y; acc.z += v.z; acc.w += v.w;
        }
        float bj = a.b1[bk->chunk_plane[s4 >> 5] * DHID_ + J];
        float4 r;
        r.x = gelu_exact(acc.x + bj);
        r.y = gelu_exact(acc.y + bj);
        r.z = gelu_exact(acc.z + bj);
        r.w = gelu_exact(acc.w + bj);
        *reinterpret_cast<float4*>(a.h1p + off) = r;
    } else if (idx < 163840) {                     // q: [256 rows][512 cols]
        int i2 = idx - 131072;
        int row = i2 >> 7, c4 = (i2 & 127) << 2;
        size_t off = (size_t)row * QH_ + c4;
        float4 acc = {0.f,0.f,0.f,0.f};
#pragma unroll
        for (int kp = 0; kp < 8; ++kp) {
            float4 v = *reinterpret_cast<const float4*>(a.q1p + (size_t)kp * 131072 + off);
            acc.x += v.x; acc.y += v.y; acc.z += v.z; acc.w += v.w;
        }
        float4 bv = *reinterpret_cast<const float4*>(a.qb1 + c4);
        float4 r;
        r.x = gelu_exact(acc.x + bv.x);
        r.y = gelu_exact(acc.y + bv.y);
        r.z = gelu_exact(acc.z + bv.z);
        r.w = gelu_exact(acc.w + bv.w);
        *reinterpret_cast<float4*>(a.q1p + off) = r;
    }
}

// K-split x8. units 0..255: q out (K=64); 256..767: content out (K=128).
__device__ void dev_l2(const KArgs& a, int u, int tid, const Buckets* bk) {
    float4 c0 = {0.f,0.f,0.f,0.f}, c1 = {0.f,0.f,0.f,0.f};
    if (u < 256) {
        int kp = u & 7, tile = u >> 3;
        int rt = tile >> 2, ct = tile & 3;
        int tr = tid >> 4, tc = tid & 15;
        int row = rt * 32 + tr * 2, col = ct * 64 + tc * 4;
        const float* a0 = a.q1p + (size_t)row * QH_ + kp * 64;   // q1 = q1p[0]
        rgemm_inner(a0, a0 + QH_, a.qw2 + (size_t)(kp * 64) * QO_ + col, QO_, 64, c0, c1);
        float* o = a.q2p + (size_t)kp * 65536;
        *reinterpret_cast<float4*>(o + (size_t)row * QO_ + col) = c0;
        *reinterpret_cast<float4*>(o + (size_t)(row + 1) * QO_ + col) = c1;
    } else {
        int b2i = u - 256;
        int kp = b2i & 7, tile = b2i >> 3;
        int c = tile >> 2, jt = tile & 3;
        if (c >= bk->nchunks) return;
        int p = bk->chunk_plane[c];
        int tr = tid >> 3, tc = tid & 7;
        int J = jt * 64 + tr * 2;
        int slot = c * 32 + tc * 4;
        const float* a0 = a.W2 + ((size_t)p * DS_ + J) * DHID_ + kp * 128;
        rgemm_inner(a0, a0 + DHID_, a.h1p + (size_t)(kp * 128) * SLOTS_ + slot, SLOTS_, 128, c0, c1);
        float* o = a.c2p + (size_t)kp * 131072;
        *reinterpret_cast<float4*>(o + (size_t)J * SLOTS_ + slot) = c0;
        *reinterpret_cast<float4*>(o + (size_t)(J + 1) * SLOTS_ + slot) = c1;
    }
}

__device__ void dev_score(const KArgs& a, int w, int tid, int t, const Buckets* bk) {
    int b = w >> 4;
    int pold = a.pos[w];              // block-local
    int slot = bk->slot_of[w];
    __shared__ float qv_s[256];
    __shared__ int nbr_s[32];
    __shared__ float part_s[8][32];
    __shared__ float sc_s[32];
    if (tid < 32) nbr_s[tid] = a.neighbors[(size_t)pold * K_ + tid];
    float qsum = a.qb2[tid];
#pragma unroll
    for (int kp = 0; kp < 8; ++kp) qsum += a.q2p[(size_t)kp * 65536 + (size_t)w * QO_ + tid];
    qv_s[tid] = qsum;
    float csum = a.b2[bk->chunk_plane[slot >> 5] * DS_ + tid];
#pragma unroll
    for (int kp = 0; kp < 8; ++kp) csum += a.c2p[(size_t)kp * 131072 + (size_t)tid * SLOTS_ + slot];
    __syncthreads();
    int k = tid & 31, part = tid >> 5;
    int nk = nbr_s[k];
    const float* kp_ = a.keys + (size_t)nk * 256 + part * 32;
    const float* qp = qv_s + part * 32;
    float acc = 0.f;
#pragma unroll
    for (int i = 0; i < 32; i += 4) {
        float4 kv = *reinterpret_cast<const float4*>(kp_ + i);
        acc += kv.x * qp[i] + kv.y * qp[i+1] + kv.z * qp[i+2] + kv.w * qp[i+3];
    }
    part_s[part][k] = acc;
    __syncthreads();
    if (tid < 32) {
        float s = 0.f;
#pragma unroll
        for (int p8 = 0; p8 < 8; ++p8) s += part_s[p8][tid];
        sc_s[tid] = s * SCORE_SCALE;
    }
    __syncthreads();
    if (tid < 32) {
        float sv = sc_s[tid];
        float m = sv;
        for (int off = 1; off < 32; off <<= 1) m = fmaxf(m, __shfl_xor(m, off));
        float e = expf(sv - m);
        float ssum = e;
        for (int off = 1; off < 32; off <<= 1) ssum += __shfl_xor(ssum, off);
        float prob = e / ssum;
        atomicAdd(&a.mp_all[t * 32 + tid], prob);
        float bs = sv; int bi = tid;
        for (int off = 1; off < 32; off <<= 1) {
            float os = __shfl_xor(bs, off);
            int   oi = __shfl_xor(bi, off);
            if (os > bs || (os == bs && oi < bi)) { bs = os; bi = oi; }
        }
        if (tid == 0) {
            int next = nbr_s[bi];
            a.pos[w] = next;                      // block-local write
            if (t == T_ - 1) a.out_pos[w] = (float)next;   // final pos, block-local
            atomicAdd(&a.out_co[(size_t)pold * N_ + next], 1.0f);
            atomicAdd(&a.out_vc[next], 1.0f);
        }
    }
    atomicAdd(&a.out_s[((size_t)b * N_ + pold) * DS_ + tid], csum);
    float wn = a.out_ws[(size_t)w * DS_ + tid] + csum;
    a.out_ws[(size_t)w * DS_ + tid] = wn;
    atomicAdd(&a.out_motor[((size_t)b * T_ + t) * DS_ + tid], wn * (1.0f / H_));
    __syncthreads();
}

__device__ void dev_final_lb(const KArgs& a, int tid) {
    // atomic read of atomically-accumulated mp_all (cross-XCD coherent)
    float v = atomicAdd(&a.mp_all[tid], 0.f) * (1.0f / 256.f);
    v = v * v;
    for (int off = 32; off > 0; off >>= 1) v += __shfl_down(v, off);
    __shared__ float red[4];
    if ((tid & 63) == 0) red[tid >> 6] = v;
    __syncthreads();
    if (tid == 0) a.out_lb[0] = (float)K_ * (red[0] + red[1] + red[2] + red[3]);
}

// ---------------- cooperative mega kernel ----------------

__global__ __launch_bounds__(256, 4) void mega_kernel(KArgs a)
{
    cg::grid_group grid = cg::this_grid();
    const int bid = blockIdx.x, nb = gridDim.x, tid = threadIdx.x;
    __shared__ Buckets bk;
    build_buckets(a.plane_idx, tid, &bk);

#define GSYNC() { __threadfence(); grid.sync(); }

    // phase 0: output init + pos init (walker->block mapping) + keysA
    dev_biginit(a, bid * 256 + tid, nb * 256);
    for (int u = bid; u < 256; u += nb) {
        if (tid == 0) a.pos[u] = a.walker_pos[u];
        if (tid < 32) atomicExch(&a.mp_all[(tid & 7) * 32 + (u & 31)], 0.f);
    }
    // simpler full mp zero (atomic, idempotent):
    if (bid == 0) atomicExch(&a.mp_all[tid], 0.f);
    for (int u = bid; u < 1024; u += nb) dev_keysA(a, u, tid);
    GSYNC();
    // phase 1: steer(0) on canonical mapping || keysB on shifted units
    for (int u = bid; u < 768; u += nb) {
        if (u < 256) dev_steer(a, u, tid, 0, &bk);
        else dev_keysB(a, u - 256, tid);
    }
    GSYNC();

    for (int t = 0; t < T_; ++t) {
        for (int u = bid; u < 2560; u += nb) dev_l1(a, u, tid, &bk);
        GSYNC();
        for (int idx = bid * 256 + tid; idx < 163840; idx += nb * 256) dev_comb1(a, idx, &bk);
        GSYNC();
        for (int u = bid; u < 768; u += nb) dev_l2(a, u, tid, &bk);
        GSYNC();
        for (int u = bid; u < 256; u += nb) dev_score(a, u, tid, t, &bk);
        GSYNC();
        if (t < T_ - 1) {
            for (int u = bid; u < 256; u += nb) dev_steer(a, u, tid, t + 1, &bk);
            GSYNC();
        }
    }
    if (bid == 0) dev_final_lb(a, tid);
#undef GSYNC
}

// ---------------- fallback wrappers (non-cooperative path) ----------------

__global__ __launch_bounds__(256) void g_biginit(KArgs a) {
    dev_biginit(a, blockIdx.x * 256 + threadIdx.x, gridDim.x * 256);
    if (blockIdx.x == 0) {
        if (threadIdx.x < 256) a.pos[threadIdx.x] = a.walker_pos[threadIdx.x];
        atomicExch(&a.mp_all[threadIdx.x], 0.f);
    }
}
__global__ __launch_bounds__(256) void g_keysA(KArgs a) { dev_keysA(a, blockIdx.x, threadIdx.x); }
__global__ __launch_bounds__(256) void g_keysB(KArgs a) { dev_keysB(a, blockIdx.x, threadIdx.x); }
__global__ __launch_bounds__(256) void g_steer(KArgs a, int t) {
    __shared__ Buckets bk; build_buckets(a.plane_idx, threadIdx.x, &bk);
    dev_steer(a, blockIdx.x, threadIdx.x, t, &bk);
}
__global__ __launch_bounds__(256) void g_l1(KArgs a) {
    __shared__ Buckets bk; build_buckets(a.plane_idx, threadIdx.x, &bk);
    dev_l1(a, blockIdx.x, threadIdx.x, &bk);
}
__global__ __launch_bounds__(256) void g_comb1(KArgs a) {
    __shared__ Buckets bk; build_buckets(a.plane_idx, threadIdx.x, &bk);
    dev_comb1(a, blockIdx.x * 256 + threadIdx.x, &bk);
}
__global__ __launch_bounds__(256) void g_l2(KArgs a) {
    __shared__ Buckets bk; build_buckets(a.plane_idx, threadIdx.x, &bk);
    dev_l2(a, blockIdx.x, threadIdx.x, &bk);
}
__global__ __launch_bounds__(256) void g_score(KArgs a, int t) {
    __shared__ Buckets bk; build_buckets(a.plane_idx, threadIdx.x, &bk);
    dev_score(a, blockIdx.x, threadIdx.x, t, &bk);
}
__global__ __launch_bounds__(256) void g_final(KArgs a) { dev_final_lb(a, threadIdx.x); }

// ---------------- launch ----------------

extern "C" void kernel_launch(void* const* d_in, const int* in_sizes, int n_in,
                              void* d_out, int out_size, void* d_ws, size_t ws_size,
                              hipStream_t stream)
{
    KArgs a;
    a.s_in    = (const float*)d_in[0];
    a.node_id = (const float*)d_in[1];
    a.ws_in   = (const float*)d_in[2];
    a.token   = (const float*)d_in[3];
    a.norm_w  = (const float*)d_in[4];
    a.W1  = (const float*)d_in[5];
    a.b1  = (const float*)d_in[6];
    a.W2  = (const float*)d_in[7];
    a.b2  = (const float*)d_in[8];
    a.qw1 = (const float*)d_in[9];
    a.qb1 = (const float*)d_in[10];
    a.qw2 = (const float*)d_in[11];
    a.qb2 = (const float*)d_in[12];
    a.kw1 = (const float*)d_in[13];
    a.kb1 = (const float*)d_in[14];
    a.kw2 = (const float*)d_in[15];
    a.kb2 = (const float*)d_in[16];
    a.walker_pos = (const int*)d_in[17];
    a.plane_idx  = (const int*)d_in[18];
    a.neighbors  = (const int*)d_in[19];

    float* out = (float*)d_out;
    a.out_motor = out;                               // 32768
    a.out_s     = a.out_motor + 32768;               // 16777216
    a.out_pos   = a.out_s + (size_t)16777216;        // 256
    a.out_ws    = a.out_pos + 256;                   // 65536
    a.out_co    = a.out_ws + 65536;                  // 16777216
    a.out_vc    = a.out_co + (size_t)16777216;       // 4096
    a.out_lb    = a.out_vc + 4096;                   // 1

    float* ws = (float*)d_ws;
    a.keys   = ws;                                   // 1048576
    a.steer  = a.keys + 1048576;                     // 229376
    a.steerT = a.steer + 229376;                     // 458752
    float* PART = a.steerT + 458752;                 // 5242880 (time-shared)
    a.kh  = PART;
    a.h1p = PART;
    a.q1p = PART + 4194304;
    a.c2p = PART + 524288;
    a.q2p = PART + 1572864;
    a.mp_all = PART + 5242880;                       // 256
    a.pos    = (int*)(a.mp_all + 256);               // 256

    int occ = 0;
    hipError_t oe = hipOccupancyMaxActiveBlocksPerMultiprocessor(
        &occ, (const void*)mega_kernel, 256, 0);
    if (oe != hipSuccess || occ < 1) occ = 4;
    long nbl = (long)occ * 256;
    int nb = (int)(nbl > 1024 ? 1024 : nbl);
    if (nb < 256) nb = 256;

    void* params[] = { (void*)&a };
    hipError_t e = hipLaunchCooperativeKernel((const void*)mega_kernel,
                                              dim3(nb), dim3(256), params, 0, stream);
    if (e != hipSuccess) {
        g_biginit<<<4096, 256, 0, stream>>>(a);
        g_keysA<<<1024, 256, 0, stream>>>(a);
        g_keysB<<<512, 256, 0, stream>>>(a);
        for (int t = 0; t < T_; ++t) {
            g_steer<<<256, 256, 0, stream>>>(a, t);
            g_l1<<<2560, 256, 0, stream>>>(a);
            g_comb1<<<640, 256, 0, stream>>>(a);
            g_l2<<<768, 256, 0, stream>>>(a);
            g_score<<<256, 256, 0, stream>>>(a, t);
        }
        g_final<<<1, 256, 0, stream>>>(a);
    }
}

// Round 8
// 548.358 us; speedup vs baseline: 9.5897x; 9.5897x over previous
//
#include <hip/hip_runtime.h>
#include <math.h>

#define B_    16
#define H_    16
#define N_    4096
#define T_    8
#define DS_   256
#define DID_  128
#define L_    8
#define K_    32
#define DHID_ 1024
#define DSTEER_ 896
#define QH_   512
#define QO_   256
#define NW_   256   // B*H walkers
#define SLOTS_ 512  // chunk-slot space: 16 chunks x 32 slots
#define SCORE_SCALE 0.022097086912079608f  // 1/(8*sqrt(32))

struct KArgs {
    const float *s_in, *node_id, *ws_in, *token, *norm_w;
    const float *W1, *b1, *W2, *b2;
    const float *qw1, *qb1, *qw2, *qb2, *kw1, *kb1, *kw2, *kb2;
    const int *walker_pos, *plane_idx, *neighbors;
    float *out_motor, *out_s, *out_pos, *out_ws, *out_co, *out_vc, *out_lb;
    float *keys, *kh, *steer, *steerT, *h1p, *q1p, *c2p, *q2p, *mp_all;
    int *pos, *plane_order, *chunk_plane, *chunk_rows, *slot_of, *nchunks;
};

__device__ __forceinline__ float gelu_exact(float x) {
    return 0.5f * x * (1.0f + erff(x * 0.70710678118654752f));
}

#define FMA4(c, b, a) { c.x = fmaf(b.x, (a), c.x); c.y = fmaf(b.y, (a), c.y); \
                        c.z = fmaf(b.z, (a), c.z); c.w = fmaf(b.w, (a), c.w); }

__device__ __forceinline__ void gelu4(float4& v) {
    v.x = gelu_exact(v.x); v.y = gelu_exact(v.y);
    v.z = gelu_exact(v.z); v.w = gelu_exact(v.w);
}

// acc[2 rows][4 cols] += A[2 rows][K] * B[K][4 cols]; B may live in LDS.
__device__ __forceinline__ void rgemm_inner(
    const float* __restrict__ a0, const float* __restrict__ a1,
    const float* bp, int ldb, int K,
    float4& c0, float4& c1)
{
    for (int k = 0; k < K; k += 8) {
        const float4 a0l = *reinterpret_cast<const float4*>(a0 + k);
        const float4 a0h = *reinterpret_cast<const float4*>(a0 + k + 4);
        const float4 a1l = *reinterpret_cast<const float4*>(a1 + k);
        const float4 a1h = *reinterpret_cast<const float4*>(a1 + k + 4);
        const float* b8 = bp + (size_t)k * ldb;
#define KSTEP(o, av0, av1) { float4 bv = *reinterpret_cast<const float4*>(b8 + (size_t)(o) * ldb); \
                             FMA4(c0, bv, av0); FMA4(c1, bv, av1); }
        KSTEP(0, a0l.x, a1l.x)
        KSTEP(1, a0l.y, a1l.y)
        KSTEP(2, a0l.z, a1l.z)
        KSTEP(3, a0l.w, a1l.w)
        KSTEP(4, a0h.x, a1h.x)
        KSTEP(5, a0h.y, a1h.y)
        KSTEP(6, a0h.z, a1h.z)
        KSTEP(7, a0h.w, a1h.w)
#undef KSTEP
    }
}

// ---------------- setup1: biginit (4096) + tables (1) + keysA (1024) --------

__global__ __launch_bounds__(256) void setup1_kernel(KArgs a)
{
    int bid = blockIdx.x, tid = threadIdx.x;
    if (bid < 4096) {
        int gid = bid * 256 + tid, stride = 4096 * 256;
        const float4 z = {0.f, 0.f, 0.f, 0.f};
        float4* co4 = reinterpret_cast<float4*>(a.out_co);
        float4* s4o = reinterpret_cast<float4*>(a.out_s);
        const float4* s4i = reinterpret_cast<const float4*>(a.s_in);
        for (int i = gid; i < 4194304; i += stride) co4[i] = z;
        for (int i = gid; i < 4194304; i += stride) s4o[i] = s4i[i];
        float4* m4 = reinterpret_cast<float4*>(a.out_motor);
        for (int i = gid; i < 8192; i += stride) m4[i] = z;
        float4* w4o = reinterpret_cast<float4*>(a.out_ws);
        const float4* w4i = reinterpret_cast<const float4*>(a.ws_in);
        for (int i = gid; i < 16384; i += stride) w4o[i] = w4i[i];
        float4* v4 = reinterpret_cast<float4*>(a.out_vc);
        for (int i = gid; i < 1024; i += stride) v4[i] = z;
        if (gid == 0) a.out_lb[0] = 0.f;
    } else if (bid == 4096) {
        // walker bucketing tables + pos/mp init (single block)
        a.pos[tid] = a.walker_pos[tid];
        a.mp_all[tid] = 0.f;
        __shared__ int cnt_s[8];
        __shared__ int cplane_s[16], cbase_s[16];
        __shared__ int nch_s;
        int wave = tid >> 6, lane = tid & 63;
        for (int pp = wave; pp < 8; pp += 4) {
            int base = 0;
            for (int c0 = 0; c0 < NW_; c0 += 64) {
                int w = c0 + lane;
                bool hit = (a.plane_idx[w] == pp);
                unsigned long long mask = __ballot(hit);
                if (hit) {
                    int rank = __popcll(mask & ((1ull << lane) - 1ull));
                    a.plane_order[pp * NW_ + base + rank] = w;
                }
                base += __popcll(mask);
            }
            if (lane == 0) cnt_s[pp] = base;
        }
        __syncthreads();
        if (tid == 0) {
            int nc = 0;
            for (int p = 0; p < 8; ++p)
                for (int s0 = 0; s0 < cnt_s[p]; s0 += 32) {
                    cplane_s[nc] = p; cbase_s[nc] = s0; ++nc;
                }
            *a.nchunks = nc;
            nch_s = nc;
        }
        __syncthreads();
        int nc = nch_s;
        for (int idx = tid; idx < 512; idx += 256) {
            int c = idx >> 5, i = idx & 31;
            int v = -1;
            if (c < nc) {
                int p = cplane_s[c];
                int r = cbase_s[c] + i;
                if (r < cnt_s[p]) v = a.plane_order[p * NW_ + r];
            }
            a.chunk_rows[c * 32 + i] = v;
            if (v >= 0) a.slot_of[v] = c * 32 + i;
            if (i == 0) a.chunk_plane[c] = (c < nc) ? cplane_s[c] : 0;
        }
    } else {
        // keysA: kh = gelu(node_id @ kw1 + kb1), unit u in [0,1024)
        int u = bid - 4097;
        int rt = u >> 3, ct = u & 7;
        int tr = tid >> 4, tc = tid & 15;
        int row = rt * 32 + tr * 2, col = ct * 64 + tc * 4;
        const float* a0 = a.node_id + (size_t)row * DID_;
        float4 c0 = {0.f,0.f,0.f,0.f}, c1 = {0.f,0.f,0.f,0.f};
        rgemm_inner(a0, a0 + DID_, a.kw1 + col, QH_, DID_, c0, c1);
        float4 bv = *reinterpret_cast<const float4*>(a.kb1 + col);
        c0.x += bv.x; c0.y += bv.y; c0.z += bv.z; c0.w += bv.w;
        c1.x += bv.x; c1.y += bv.y; c1.z += bv.z; c1.w += bv.w;
        gelu4(c0); gelu4(c1);
        *reinterpret_cast<float4*>(a.kh + (size_t)row * QH_ + col) = c0;
        *reinterpret_cast<float4*>(a.kh + (size_t)(row + 1) * QH_ + col) = c1;
    }
}

// ---------------- steer body ----------------

__device__ void dev_steer(const KArgs& a, int w, int tid, int t) {
    int b = w >> 4;
    int p = a.pos[w];
    int slot = a.slot_of[w];
    float sc = a.out_s[((size_t)b * N_ + p) * DS_ + tid];
    float v = sc * sc;
    for (int off = 32; off > 0; off >>= 1) v += __shfl_down(v, off);
    __shared__ float red[4];
    if ((tid & 63) == 0) red[tid >> 6] = v;
    __syncthreads();
    float tot = red[0] + red[1] + red[2] + red[3];
    float r = rsqrtf(tot * (1.0f / DS_) + 1e-6f);
    float* st = a.steer + (size_t)w * DSTEER_;
    float v0 = sc * r * a.norm_w[tid];
    float v2 = a.out_ws[(size_t)w * DS_ + tid];
    float v3 = a.token[((size_t)b * T_ + t) * DS_ + tid];
    st[tid] = v0;
    st[384 + tid] = v2;
    st[640 + tid] = v3;
    a.steerT[(size_t)tid * SLOTS_ + slot] = v0;
    a.steerT[(size_t)(384 + tid) * SLOTS_ + slot] = v2;
    a.steerT[(size_t)(640 + tid) * SLOTS_ + slot] = v3;
    if (tid < 128) {
        float v1 = a.node_id[(size_t)p * DID_ + tid];
        st[256 + tid] = v1;
        a.steerT[(size_t)(256 + tid) * SLOTS_ + slot] = v1;
    }
}

// ---------------- setup2: keysB (512) + steer(0) (256) ----------------

__global__ __launch_bounds__(256) void setup2_kernel(KArgs a)
{
    int bid = blockIdx.x, tid = threadIdx.x;
    if (bid < 512) {
        int rt = bid >> 2, ct = bid & 3;
        int tr = tid >> 4, tc = tid & 15;
        int row = rt * 32 + tr * 2, col = ct * 64 + tc * 4;
        const float* a0 = a.kh + (size_t)row * QH_;
        float4 c0 = {0.f,0.f,0.f,0.f}, c1 = {0.f,0.f,0.f,0.f};
        rgemm_inner(a0, a0 + QH_, a.kw2 + col, QO_, QH_, c0, c1);
        float4 bv = *reinterpret_cast<const float4*>(a.kb2 + col);
        c0.x += bv.x; c0.y += bv.y; c0.z += bv.z; c0.w += bv.w;
        c1.x += bv.x; c1.y += bv.y; c1.z += bv.z; c1.w += bv.w;
        *reinterpret_cast<float4*>(a.keys + (size_t)row * QO_ + col) = c0;
        *reinterpret_cast<float4*>(a.keys + (size_t)(row + 1) * QO_ + col) = c1;
    } else {
        dev_steer(a, bid - 512, tid, 0);
    }
}

__global__ __launch_bounds__(256) void steer_kernel(KArgs a, int t)
{
    dev_steer(a, blockIdx.x, threadIdx.x, t);
}

// ---------------- layer1: K-split x8, LDS-staged B ----------------
// blocks 0..511: q hidden (tile 32r x 64c, K=112); 512..2559: content hidden.

__global__ __launch_bounds__(256) void l1_kernel(KArgs a)
{
    __shared__ float bs[112 * 64];           // 28.7 KB (q); content uses 112*32
    int bid = blockIdx.x, tid = threadIdx.x;
    float4 c0 = {0.f,0.f,0.f,0.f}, c1 = {0.f,0.f,0.f,0.f};
    if (bid < 512) {
        int kp = bid & 7, tile = bid >> 3;
        int rt = tile >> 3, ct = tile & 7;
        int tr = tid >> 4, tc = tid & 15;
        int row = rt * 32 + tr * 2, col0 = ct * 64;
        // stage B = qw1[kp*112 .. +112][col0 .. +64]
#pragma unroll
        for (int i = 0; i < 7; ++i) {
            int idx = tid + i * 256;             // 1792 float4s
            int kk = idx >> 4, c4 = (idx & 15) << 2;
            *reinterpret_cast<float4*>(bs + kk * 64 + c4) =
                *reinterpret_cast<const float4*>(a.qw1 + (size_t)(kp * 112 + kk) * QH_ + col0 + c4);
        }
        __syncthreads();
        const float* a0 = a.steer + (size_t)row * DSTEER_ + kp * 112;
        rgemm_inner(a0, a0 + DSTEER_, bs + tc * 4, 64, 112, c0, c1);
        float* o = a.q1p + (size_t)kp * 131072;
        int col = col0 + tc * 4;
        *reinterpret_cast<float4*>(o + (size_t)row * QH_ + col) = c0;
        *reinterpret_cast<float4*>(o + (size_t)(row + 1) * QH_ + col) = c1;
    } else {
        int b2 = bid - 512;
        int kp = b2 & 7, tile = b2 >> 3;
        int c = tile >> 4, jt = tile & 15;
        if (c >= *a.nchunks) return;
        int p = a.chunk_plane[c];
        int tr = tid >> 3, tc = tid & 7;
        int J = jt * 64 + tr * 2;
        // stage B = steerT[kp*112 .. +112][c*32 .. +32]
#pragma unroll
        for (int i = 0; i < 4; ++i) {
            int idx = tid + i * 256;             // 896 float4s
            if (idx < 896) {
                int kk = idx >> 3, s4 = (idx & 7) << 2;
                *reinterpret_cast<float4*>(bs + kk * 32 + s4) =
                    *reinterpret_cast<const float4*>(a.steerT + (size_t)(kp * 112 + kk) * SLOTS_ + c * 32 + s4);
            }
        }
        __syncthreads();
        const float* a0 = a.W1 + ((size_t)p * DHID_ + J) * DSTEER_ + kp * 112;
        rgemm_inner(a0, a0 + DSTEER_, bs + tc * 4, 32, 112, c0, c1);
        float* o = a.h1p + (size_t)kp * 524288;
        int slot = c * 32 + tc * 4;
        *reinterpret_cast<float4*>(o + (size_t)J * SLOTS_ + slot) = c0;
        *reinterpret_cast<float4*>(o + (size_t)(J + 1) * SLOTS_ + slot) = c1;
    }
}

// ---------------- layer2 fused: combine partials (+bias+gelu) into LDS, GEMM.
// blocks 0..255: q out (stage A from q1p); 256..767: content out (stage B from h1p).

__global__ __launch_bounds__(256) void l2f_kernel(KArgs a)
{
    __shared__ float smem[4096];             // 16 KB; q uses 32*72=2304
    int bid = blockIdx.x, tid = threadIdx.x;
    float4 c0 = {0.f,0.f,0.f,0.f}, c1 = {0.f,0.f,0.f,0.f};
    if (bid < 256) {
        int kp = bid & 7, tile = bid >> 3;
        int rt = tile >> 2, ct = tile & 3;
        int tr = tid >> 4, tc = tid & 15;
        int row0 = rt * 32, col = ct * 64 + tc * 4;
        // stage A[32][64] (pad to 72): A[r][k] = gelu(qb1 + sum_8 q1p)
#pragma unroll
        for (int i = 0; i < 2; ++i) {
            int idx = tid + i * 256;             // 512 float4s
            int r = idx >> 4, k4 = (idx & 15) << 2;
            size_t off = (size_t)(row0 + r) * QH_ + kp * 64 + k4;
            float4 acc = *reinterpret_cast<const float4*>(a.qb1 + kp * 64 + k4);
#pragma unroll
            for (int p8 = 0; p8 < 8; ++p8) {
                float4 v = *reinterpret_cast<const float4*>(a.q1p + (size_t)p8 * 131072 + off);
                acc.x += v.x; acc.y += v.y; acc.z += v.z; acc.w += v.w;
            }
            gelu4(acc);
            *reinterpret_cast<float4*>(smem + r * 72 + k4) = acc;
        }
        __syncthreads();
        const float* a0 = smem + (tr * 2) * 72;
        rgemm_inner(a0, a0 + 72, a.qw2 + (size_t)(kp * 64) * QO_ + col, QO_, 64, c0, c1);
        float* o = a.q2p + (size_t)kp * 65536;
        int row = row0 + tr * 2;
        *reinterpret_cast<float4*>(o + (size_t)row * QO_ + col) = c0;
        *reinterpret_cast<float4*>(o + (size_t)(row + 1) * QO_ + col) = c1;
    } else {
        int b2i = bid - 256;
        int kp = b2i & 7, tile = b2i >> 3;
        int c = tile >> 2, jt = tile & 3;
        if (c >= *a.nchunks) return;
        int p = a.chunk_plane[c];
        int tr = tid >> 3, tc = tid & 7;
        int J = jt * 64 + tr * 2;
        // stage B[128][32]: B[kk][s] = gelu(b1[p][kq] + sum_8 h1p)
#pragma unroll
        for (int i = 0; i < 4; ++i) {
            int idx = tid + i * 256;             // 1024 float4s
            int kk = idx >> 3, s4 = (idx & 7) << 2;
            int kq = kp * 128 + kk;
            size_t off = (size_t)kq * SLOTS_ + c * 32 + s4;
            float bj = a.b1[p * DHID_ + kq];
            float4 acc = {bj, bj, bj, bj};
#pragma unroll
            for (int p8 = 0; p8 < 8; ++p8) {
                float4 v = *reinterpret_cast<const float4*>(a.h1p + (size_t)p8 * 524288 + off);
                acc.x += v.x; acc.y += v.y; acc.z += v.z; acc.w += v.w;
            }
            gelu4(acc);
            *reinterpret_cast<float4*>(smem + kk * 32 + s4) = acc;
        }
        __syncthreads();
        const float* a0 = a.W2 + ((size_t)p * DS_ + J) * DHID_ + kp * 128;
        rgemm_inner(a0, a0 + DHID_, smem + tc * 4, 32, 128, c0, c1);
        float* o = a.c2p + (size_t)kp * 131072;
        int slot = c * 32 + tc * 4;
        *reinterpret_cast<float4*>(o + (size_t)J * SLOTS_ + slot) = c0;
        *reinterpret_cast<float4*>(o + (size_t)(J + 1) * SLOTS_ + slot) = c1;
    }
}

// ---------------- score: sum l2 partials, softmax/argmax, state updates -----

__global__ __launch_bounds__(256) void score_kernel(KArgs a, int t)
{
    int w = blockIdx.x;
    int b = w >> 4;
    int tid = threadIdx.x;
    int pold = a.pos[w];
    int slot = a.slot_of[w];
    __shared__ float qv_s[256];
    __shared__ int nbr_s[32];
    __shared__ float part_s[8][32];
    __shared__ float sc_s[32];
    if (tid < 32) nbr_s[tid] = a.neighbors[(size_t)pold * K_ + tid];
    float qsum = a.qb2[tid];
#pragma unroll
    for (int kp = 0; kp < 8; ++kp) qsum += a.q2p[(size_t)kp * 65536 + (size_t)w * QO_ + tid];
    qv_s[tid] = qsum;
    float csum = a.b2[a.chunk_plane[slot >> 5] * DS_ + tid];
#pragma unroll
    for (int kp = 0; kp < 8; ++kp) csum += a.c2p[(size_t)kp * 131072 + (size_t)tid * SLOTS_ + slot];
    __syncthreads();
    int k = tid & 31, part = tid >> 5;
    int nk = nbr_s[k];
    const float* kp_ = a.keys + (size_t)nk * 256 + part * 32;
    const float* qp = qv_s + part * 32;
    float acc = 0.f;
#pragma unroll
    for (int i = 0; i < 32; i += 4) {
        float4 kv = *reinterpret_cast<const float4*>(kp_ + i);
        acc += kv.x * qp[i] + kv.y * qp[i+1] + kv.z * qp[i+2] + kv.w * qp[i+3];
    }
    part_s[part][k] = acc;
    __syncthreads();
    if (tid < 32) {
        float s = 0.f;
#pragma unroll
        for (int p8 = 0; p8 < 8; ++p8) s += part_s[p8][tid];
        sc_s[tid] = s * SCORE_SCALE;
    }
    __syncthreads();
    if (tid < 32) {
        float sv = sc_s[tid];
        float m = sv;
        for (int off = 1; off < 32; off <<= 1) m = fmaxf(m, __shfl_xor(m, off));
        float e = expf(sv - m);
        float ssum = e;
        for (int off = 1; off < 32; off <<= 1) ssum += __shfl_xor(ssum, off);
        float prob = e / ssum;
        atomicAdd(&a.mp_all[t * 32 + tid], prob);
        float bs = sv; int bi = tid;
        for (int off = 1; off < 32; off <<= 1) {
            float os = __shfl_xor(bs, off);
            int   oi = __shfl_xor(bi, off);
            if (os > bs || (os == bs && oi < bi)) { bs = os; bi = oi; }
        }
        if (tid == 0) {
            int next = nbr_s[bi];
            a.pos[w] = next;
            if (t == T_ - 1) a.out_pos[w] = (float)next;
            atomicAdd(&a.out_co[(size_t)pold * N_ + next], 1.0f);
            atomicAdd(&a.out_vc[next], 1.0f);
        }
    }
    atomicAdd(&a.out_s[((size_t)b * N_ + pold) * DS_ + tid], csum);
    float wn = a.out_ws[(size_t)w * DS_ + tid] + csum;
    a.out_ws[(size_t)w * DS_ + tid] = wn;
    atomicAdd(&a.out_motor[((size_t)b * T_ + t) * DS_ + tid], wn * (1.0f / H_));
}

__global__ __launch_bounds__(256) void final_kernel(KArgs a)
{
    int tid = threadIdx.x;
    float v = a.mp_all[tid] * (1.0f / 256.f);
    v = v * v;
    for (int off = 32; off > 0; off >>= 1) v += __shfl_down(v, off);
    __shared__ float red[4];
    if ((tid & 63) == 0) red[tid >> 6] = v;
    __syncthreads();
    if (tid == 0) a.out_lb[0] = (float)K_ * (red[0] + red[1] + red[2] + red[3]);
}

// ---------------- launch ----------------

extern "C" void kernel_launch(void* const* d_in, const int* in_sizes, int n_in,
                              void* d_out, int out_size, void* d_ws, size_t ws_size,
                              hipStream_t stream)
{
    KArgs a;
    a.s_in    = (const float*)d_in[0];
    a.node_id = (const float*)d_in[1];
    a.ws_in   = (const float*)d_in[2];
    a.token   = (const float*)d_in[3];
    a.norm_w  = (const float*)d_in[4];
    a.W1  = (const float*)d_in[5];
    a.b1  = (const float*)d_in[6];
    a.W2  = (const float*)d_in[7];
    a.b2  = (const float*)d_in[8];
    a.qw1 = (const float*)d_in[9];
    a.qb1 = (const float*)d_in[10];
    a.qw2 = (const float*)d_in[11];
    a.qb2 = (const float*)d_in[12];
    a.kw1 = (const float*)d_in[13];
    a.kb1 = (const float*)d_in[14];
    a.kw2 = (const float*)d_in[15];
    a.kb2 = (const float*)d_in[16];
    a.walker_pos = (const int*)d_in[17];
    a.plane_idx  = (const int*)d_in[18];
    a.neighbors  = (const int*)d_in[19];

    float* out = (float*)d_out;
    a.out_motor = out;                               // 32768
    a.out_s     = a.out_motor + 32768;               // 16777216
    a.out_pos   = a.out_s + (size_t)16777216;        // 256
    a.out_ws    = a.out_pos + 256;                   // 65536
    a.out_co    = a.out_ws + 65536;                  // 16777216
    a.out_vc    = a.out_co + (size_t)16777216;       // 4096
    a.out_lb    = a.out_vc + 4096;                   // 1

    // workspace (floats); h1p/q1p/c2p/q2p disjoint (no comb overwrite now);
    // kh (setup-only) aliases h1p.
    float* ws = (float*)d_ws;
    a.keys   = ws;                                   // 1,048,576
    a.steer  = a.keys + 1048576;                     // 229,376
    a.steerT = a.steer + 229376;                     // 458,752
    a.h1p    = a.steerT + 458752;                    // 4,194,304
    a.kh     = a.h1p;                                // alias (2,097,152 <= h1p)
    a.q1p    = a.h1p + 4194304;                      // 1,048,576
    a.c2p    = a.q1p + 1048576;                      // 1,048,576
    a.q2p    = a.c2p + 1048576;                      // 524,288
    a.mp_all = a.q2p + 524288;                       // 256
    a.pos         = (int*)(a.mp_all + 256);          // 256
    a.plane_order = a.pos + 256;                     // 2048
    a.chunk_plane = a.plane_order + 2048;            // 16
    a.chunk_rows  = a.chunk_plane + 16;              // 512
    a.slot_of     = a.chunk_rows + 512;              // 256
    a.nchunks     = a.slot_of + 256;                 // 1
    // total ~8.56M floats ~= 34.3 MB

    setup1_kernel<<<4096 + 1 + 1024, 256, 0, stream>>>(a);
    setup2_kernel<<<512 + 256, 256, 0, stream>>>(a);
    for (int t = 0; t < T_; ++t) {
        l1_kernel<<<2560, 256, 0, stream>>>(a);
        l2f_kernel<<<768, 256, 0, stream>>>(a);
        score_kernel<<<256, 256, 0, stream>>>(a, t);
        if (t < T_ - 1) steer_kernel<<<256, 256, 0, stream>>>(a, t + 1);
    }
    final_kernel<<<1, 256, 0, stream>>>(a);
}